// Round 6
// baseline (318.834 us; speedup 1.0000x reference)
//
#include <hip/hip_runtime.h>

// TensorProductContraction: fused irrep-linear + Clebsch-Gordan re-expansion.
// Phase 1 (prep_kernel): pack x -> 12 bf16 A-panels (component-separated) and
// w -> 4 bf16 B-panels, in mfma_f32_16x16x32_bf16 fragment lane order (26.7 MB ws).
// Phase 2 (tp_main): per-wave 32Mx16V tile, K=128, swapped-operand MFMA
// (acc = W^T X^T tile: lane = one m-row, j = 4 consecutive v), in-register CG
// mix, all stores lane-contiguous dwordx4 nt.
// Round 3: block remap (4 waves share one mt2 A-slice), XCD swizzle, all-nt.
// Round 4 (reverted): plain D/B stores thrash L2 with the 384MB write stream.
// Round 5 (reverted): dwordx3 inline asm miscompiled -> wrong D values.
// Round 6: swap mfma operands (A/B slots share one lane map, so panels are
// reusable as either operand) so each lane owns 12 contiguous D floats ->
// 3x dwordx4 nt per (mf,lam); store instrs per L-wave 96 -> 24. No asm.

typedef __attribute__((ext_vector_type(8))) __bf16 bf16x8;
typedef __attribute__((ext_vector_type(8))) unsigned short u16x8;
typedef __attribute__((ext_vector_type(4))) float f32x4;

#define A_V8_TOTAL (12 * 512 * 4 * 64)  // 1,572,864 u16x8 (16B) entries = 25.2 MB
#define B_V8_TOTAL (384 * 4 * 64)       // 98,304 entries = 1.57 MB
#define P_STRIDE   (512 * 4 * 64)       // 131072 u16x8 per A panel
#define WS_NEED_BYTES ((size_t)(A_V8_TOTAL + B_V8_TOTAL) * 16)

__device__ __forceinline__ unsigned short f2bf(float f) {
  unsigned u = __builtin_bit_cast(unsigned, f);
  u = (u + 0x7FFFu + ((u >> 16) & 1u)) >> 16;  // RNE
  return (unsigned short)u;
}

__device__ __forceinline__ f32x4 mfma16(bf16x8 a, bf16x8 b, f32x4 c) {
  return __builtin_amdgcn_mfma_f32_16x16x32_bf16(a, b, c, 0, 0, 0);
}
__device__ __forceinline__ bf16x8 asbf(u16x8 v) { return __builtin_bit_cast(bf16x8, v); }
__device__ __forceinline__ void stnt4(float* p, f32x4 v) {
  __builtin_nontemporal_store(v, (f32x4*)p);   // global_store_dwordx4 ... nt
}

// ---------------- prep: f32 -> bf16 fragment-packed panels ----------------
__global__ __launch_bounds__(256) void prep_kernel(
    const float* __restrict__ x, const float* __restrict__ w0e,
    const float* __restrict__ w1o, const float* __restrict__ w1e,
    const float* __restrict__ w2e, u16x8* __restrict__ ws) {
  int t = blockIdx.x * 256 + threadIdx.x;
  if (t < A_V8_TOTAL) {
    int l = t & 63;
    int kb = (t >> 6) & 3;
    int mt = (t >> 8) & 511;
    int p = t >> 17;
    int m = mt * 16 + (l & 15);
    int k0 = kb * 32 + (l >> 4) * 8;
    int base, d, comp;
    if (p == 0)      { base = 0;   d = 1; comp = 0;     }
    else if (p < 4)  { base = 128; d = 3; comp = p - 1; }
    else if (p < 7)  { base = 512; d = 3; comp = p - 4; }
    else             { base = 896; d = 5; comp = p - 7; }
    const float* xr = x + (size_t)m * 1536 + base + comp + k0 * d;
    u16x8 v;
#pragma unroll
    for (int e = 0; e < 8; ++e) v[e] = f2bf(xr[e * d]);
    ws[t] = v;
  } else {
    int tb = t - A_V8_TOTAL;
    if (tb >= B_V8_TOTAL) return;
    int l = tb & 63;
    int kb = (tb >> 6) & 3;
    int ci = tb >> 8;
    const float* w; int N, v0;
    if (ci < 128)      { w = w0e; N = 2048; v0 = ci * 16;         }
    else if (ci < 256) { w = w1o; N = 2048; v0 = (ci - 128) * 16; }
    else if (ci < 320) { w = w1e; N = 1024; v0 = (ci - 256) * 16; }
    else               { w = w2e; N = 1024; v0 = (ci - 320) * 16; }
    int n = v0 + (l & 15);
    int k0 = kb * 32 + (l >> 4) * 8;
    u16x8 v;
#pragma unroll
    for (int e = 0; e < 8; ++e) v[e] = f2bf(w[(size_t)(k0 + e) * N + n]);
    ws[A_V8_TOTAL + tb] = v;
  }
}

// ---------------- main fused kernel ----------------
// Block = 4 waves sharing one mt2 (32-row A-slice), each wave a different vt.
// Swapped MFMA: acc[mf][p][j] = y_p[m = mt2*32+mf*16+(l&15), v = vt*16+(l>>4)*4+j]
__global__ __launch_bounds__(256) void tp_main(const u16x8* __restrict__ ws,
                                               float* __restrict__ out) {
  const int l = threadIdx.x & 63;
  const int wv = threadIdx.x >> 6;
  const int bid = blockIdx.x;
  const int logical = (bid & 7) * 1024 + (bid >> 3);  // 8192 blocks, bijective
  const int mt2 = logical >> 5;                       // 0..255 (32-row tiles)
  const int vt = ((logical & 31) << 2) | wv;          // 0..127
  const int l15 = l & 15, lhi = l >> 4;
  const u16x8* Ap = ws;
  const u16x8* Bp = ws + A_V8_TOTAL;

  const float c3  = 0.57735026918962576f;   // 1/sqrt(3)
  const float c6  = 0.40824829046386302f;   // 1/sqrt(6)
  const float c10 = 0.31622776601683794f;   // 1/sqrt(10)
  const float c30 = 0.18257418583505537f;   // 1/sqrt(30)

  if (vt < 64) {
    // ---- region L: y0[v], y1o[v,0:3], y1e[v,0:3], y2e[v,0:5] -> C + D blocks
    f32x4 acc[2][12];
#pragma unroll
    for (int mf = 0; mf < 2; ++mf)
#pragma unroll
      for (int p = 0; p < 12; ++p) acc[mf][p] = (f32x4)(0.0f);

    const int ci0 = vt, ci1 = 128 + vt, ci2 = 256 + vt, ci3 = 320 + vt;
#pragma unroll
    for (int kb = 0; kb < 4; ++kb) {
      bf16x8 b0 = asbf(Bp[((ci0 << 2) + kb) * 64 + l]);
      bf16x8 b1 = asbf(Bp[((ci1 << 2) + kb) * 64 + l]);
      bf16x8 b2 = asbf(Bp[((ci2 << 2) + kb) * 64 + l]);
      bf16x8 b3 = asbf(Bp[((ci3 << 2) + kb) * 64 + l]);
#pragma unroll
      for (int mf = 0; mf < 2; ++mf) {
        const u16x8* ar = Ap + (((((mt2 << 1) | mf) << 2) + kb) << 6) + l;
        // swapped operands: w-frag in A slot, x-frag in B slot
        acc[mf][0]  = mfma16(b0, asbf(ar[0]),             acc[mf][0]);
        acc[mf][1]  = mfma16(b1, asbf(ar[1 * P_STRIDE]),  acc[mf][1]);
        acc[mf][2]  = mfma16(b1, asbf(ar[2 * P_STRIDE]),  acc[mf][2]);
        acc[mf][3]  = mfma16(b1, asbf(ar[3 * P_STRIDE]),  acc[mf][3]);
        acc[mf][4]  = mfma16(b2, asbf(ar[4 * P_STRIDE]),  acc[mf][4]);
        acc[mf][5]  = mfma16(b2, asbf(ar[5 * P_STRIDE]),  acc[mf][5]);
        acc[mf][6]  = mfma16(b2, asbf(ar[6 * P_STRIDE]),  acc[mf][6]);
        acc[mf][7]  = mfma16(b3, asbf(ar[7 * P_STRIDE]),  acc[mf][7]);
        acc[mf][8]  = mfma16(b3, asbf(ar[8 * P_STRIDE]),  acc[mf][8]);
        acc[mf][9]  = mfma16(b3, asbf(ar[9 * P_STRIDE]),  acc[mf][9]);
        acc[mf][10] = mfma16(b3, asbf(ar[10 * P_STRIDE]), acc[mf][10]);
        acc[mf][11] = mfma16(b3, asbf(ar[11 * P_STRIDE]), acc[mf][11]);
      }
    }
    // epilogue: lane owns m = mt2*32+mf*16+l15, v31 base vb = (vt&1)*16+lhi*4
    const int v5 = vt >> 1;
    const int vb = ((vt & 1) << 4) | (lhi << 2);
#pragma unroll
    for (int mf = 0; mf < 2; ++mf) {
      const int m = mt2 * 32 + mf * 16 + l15;
      float* orow = out + (size_t)m * 16384;
      float* oc = orow + 4096 + v5 * 96 + vb;
      // C: one dwordx4 per lam (4 consecutive v31 per lane)
      f32x4 cc;
#pragma unroll
      for (int j = 0; j < 4; ++j) cc[j] = acc[mf][1][j] * c3;
      stnt4(oc + 0, cc);
#pragma unroll
      for (int j = 0; j < 4; ++j) cc[j] = acc[mf][2][j] * c3;
      stnt4(oc + 32, cc);
#pragma unroll
      for (int j = 0; j < 4; ++j) cc[j] = acc[mf][3][j] * c3;
      stnt4(oc + 64, cc);
      // D: 9 values per (j); 12 contiguous floats per lam -> 3 dwordx4
      float D9[4][9];
#pragma unroll
      for (int j = 0; j < 4; ++j) {
        const float s  = acc[mf][0][j] * c3;
        const float e0 = acc[mf][4][j], e1 = acc[mf][5][j], e2 = acc[mf][6][j];
        const float q0 = acc[mf][7][j], q1 = acc[mf][8][j];
        const float q2 = acc[mf][9][j], q3 = acc[mf][10][j], q4 = acc[mf][11][j];
        // cg(1,1,1) = -eps/sqrt(6) (reference SVD sign)
        D9[j][0] = s - q2 * c30 - q4 * c10;
        D9[j][1] = -e2 * c6 + q1 * c10;
        D9[j][2] = e1 * c6 + q0 * c10;
        D9[j][3] = e2 * c6 + q1 * c10;
        D9[j][4] = s + 2.0f * q2 * c30;
        D9[j][5] = -e0 * c6 + q3 * c10;
        D9[j][6] = -e1 * c6 + q0 * c10;
        D9[j][7] = e0 * c6 + q3 * c10;
        D9[j][8] = s - q2 * c30 + q4 * c10;
      }
#pragma unroll
      for (int lam = 0; lam < 3; ++lam) {
        float* od = orow + 7168 + v5 * 288 + lam * 96 + vb * 3;
        f32x4 f0 = {D9[0][lam*3+0], D9[0][lam*3+1], D9[0][lam*3+2], D9[1][lam*3+0]};
        f32x4 f1 = {D9[1][lam*3+1], D9[1][lam*3+2], D9[2][lam*3+0], D9[2][lam*3+1]};
        f32x4 f2 = {D9[2][lam*3+2], D9[3][lam*3+0], D9[3][lam*3+1], D9[3][lam*3+2]};
        stnt4(od + 0, f0);
        stnt4(od + 4, f1);
        stnt4(od + 8, f2);
      }
    }
  } else {
    // ---- region H: v' = v-1024; y0[v] -> A block, y1o[v,:] -> B block
    const int vtp = vt - 64;
    f32x4 acc[2][4];
#pragma unroll
    for (int mf = 0; mf < 2; ++mf)
#pragma unroll
      for (int p = 0; p < 4; ++p) acc[mf][p] = (f32x4)(0.0f);

    const int ci0 = 64 + vtp, ci1 = 192 + vtp;
#pragma unroll
    for (int kb = 0; kb < 4; ++kb) {
      bf16x8 b0 = asbf(Bp[((ci0 << 2) + kb) * 64 + l]);
      bf16x8 b1 = asbf(Bp[((ci1 << 2) + kb) * 64 + l]);
#pragma unroll
      for (int mf = 0; mf < 2; ++mf) {
        const u16x8* ar = Ap + (((((mt2 << 1) | mf) << 2) + kb) << 6) + l;
        acc[mf][0] = mfma16(b0, asbf(ar[0]),            acc[mf][0]);
        acc[mf][1] = mfma16(b1, asbf(ar[1 * P_STRIDE]), acc[mf][1]);
        acc[mf][2] = mfma16(b1, asbf(ar[2 * P_STRIDE]), acc[mf][2]);
        acc[mf][3] = mfma16(b1, asbf(ar[3 * P_STRIDE]), acc[mf][3]);
      }
    }
    // lane owns m = mt2*32+mf*16+l15, vp base = vtp*16 + lhi*4
    const int vpb = vtp * 16 + (lhi << 2);
#pragma unroll
    for (int mf = 0; mf < 2; ++mf) {
      const int m = mt2 * 32 + mf * 16 + l15;
      float* orow = out + (size_t)m * 16384;
      // A block: 4 consecutive vp -> 1 dwordx4
      stnt4(orow + vpb, acc[mf][0]);
      // B block: 12 contiguous floats -> 3 dwordx4
      float T[4][3];
#pragma unroll
      for (int j = 0; j < 4; ++j) {
        T[j][0] = acc[mf][1][j] * c3;
        T[j][1] = acc[mf][2][j] * c3;
        T[j][2] = acc[mf][3][j] * c3;
      }
      float* ob = orow + 1024 + vpb * 3;
      f32x4 f0 = {T[0][0], T[0][1], T[0][2], T[1][0]};
      f32x4 f1 = {T[1][1], T[1][2], T[2][0], T[2][1]};
      f32x4 f2 = {T[2][2], T[3][0], T[3][1], T[3][2]};
      stnt4(ob + 0, f0);
      stnt4(ob + 4, f1);
      stnt4(ob + 8, f2);
    }
  }
}

extern "C" void kernel_launch(void* const* d_in, const int* in_sizes, int n_in,
                              void* d_out, int out_size, void* d_ws, size_t ws_size,
                              hipStream_t stream) {
  if (ws_size < WS_NEED_BYTES) return;  // need 26.7 MB scratch; fail visibly if absent
  const float* x   = (const float*)d_in[0];
  const float* w0e = (const float*)d_in[1];
  const float* w1o = (const float*)d_in[2];
  const float* w1e = (const float*)d_in[3];
  const float* w2e = (const float*)d_in[4];
  u16x8* ws = (u16x8*)d_ws;
  float* out = (float*)d_out;

  // prep: (A_V8_TOTAL + B_V8_TOTAL) threads = 1,671,168 = 6528 * 256 exactly
  prep_kernel<<<6528, 256, 0, stream>>>(x, w0e, w1o, w1e, w2e, ws);
  // main: 256 mt2-tiles * 32 vt-blocks = 8192 blocks of 4 waves
  tp_main<<<8192, 256, 0, stream>>>(ws, out);
}

// Round 7
// 211.107 us; speedup vs baseline: 1.5103x; 1.5103x over previous
//
#include <hip/hip_runtime.h>

// TensorProductContraction: fused irrep-linear + Clebsch-Gordan re-expansion.
// Phase 1 (prep_kernel): pack x -> 12 bf16 A-panels, w -> 4 bf16 B-panels in
// mfma_f32_16x16x32_bf16 fragment lane order (26.7 MB ws).
// Phase 2 (tp_main): per-wave 32Mx16V tile, K=128, round-3 operand order
// (acc lane = v-col), in-register CG mix, LDS-staged fully-coalesced nt drain.
// History: R3=175.7us (remap+all-nt). R4 plain D/B stores: L2 thrash, +48us.
// R5 dwordx3 asm: miscompiled. R6 operand swap: per-lane-contiguous but
// wave-scattered stores, 318us. Lesson: wave-level full-line coalescing at
// store time is what matters -> stage in LDS, drain with full-line dwordx4 nt.

typedef __attribute__((ext_vector_type(8))) __bf16 bf16x8;
typedef __attribute__((ext_vector_type(8))) unsigned short u16x8;
typedef __attribute__((ext_vector_type(4))) float f32x4;

#define A_V8_TOTAL (12 * 512 * 4 * 64)  // 25.2 MB
#define B_V8_TOTAL (384 * 4 * 64)       // 1.57 MB
#define P_STRIDE   (512 * 4 * 64)       // u16x8 per A panel
#define WS_NEED_BYTES ((size_t)(A_V8_TOTAL + B_V8_TOTAL) * 16)
#define LROW 200                        // LDS row stride (floats): 192 content + pad

__device__ __forceinline__ unsigned short f2bf(float f) {
  unsigned u = __builtin_bit_cast(unsigned, f);
  u = (u + 0x7FFFu + ((u >> 16) & 1u)) >> 16;  // RNE
  return (unsigned short)u;
}

__device__ __forceinline__ f32x4 mfma16(bf16x8 a, bf16x8 b, f32x4 c) {
  return __builtin_amdgcn_mfma_f32_16x16x32_bf16(a, b, c, 0, 0, 0);
}
__device__ __forceinline__ bf16x8 asbf(u16x8 v) { return __builtin_bit_cast(bf16x8, v); }
__device__ __forceinline__ void stnt4(float* p, f32x4 v) {
  __builtin_nontemporal_store(v, (f32x4*)p);   // global_store_dwordx4 ... nt
}
__device__ __forceinline__ void lgkm0() {
  asm volatile("s_waitcnt lgkmcnt(0)" ::: "memory");
}

// ---------------- prep: f32 -> bf16 fragment-packed panels ----------------
__global__ __launch_bounds__(256) void prep_kernel(
    const float* __restrict__ x, const float* __restrict__ w0e,
    const float* __restrict__ w1o, const float* __restrict__ w1e,
    const float* __restrict__ w2e, u16x8* __restrict__ ws) {
  int t = blockIdx.x * 256 + threadIdx.x;
  if (t < A_V8_TOTAL) {
    int l = t & 63;
    int kb = (t >> 6) & 3;
    int mt = (t >> 8) & 511;
    int p = t >> 17;
    int m = mt * 16 + (l & 15);
    int k0 = kb * 32 + (l >> 4) * 8;
    int base, d, comp;
    if (p == 0)      { base = 0;   d = 1; comp = 0;     }
    else if (p < 4)  { base = 128; d = 3; comp = p - 1; }
    else if (p < 7)  { base = 512; d = 3; comp = p - 4; }
    else             { base = 896; d = 5; comp = p - 7; }
    const float* xr = x + (size_t)m * 1536 + base + comp + k0 * d;
    u16x8 v;
#pragma unroll
    for (int e = 0; e < 8; ++e) v[e] = f2bf(xr[e * d]);
    ws[t] = v;
  } else {
    int tb = t - A_V8_TOTAL;
    if (tb >= B_V8_TOTAL) return;
    int l = tb & 63;
    int kb = (tb >> 6) & 3;
    int ci = tb >> 8;
    const float* w; int N, v0;
    if (ci < 128)      { w = w0e; N = 2048; v0 = ci * 16;         }
    else if (ci < 256) { w = w1o; N = 2048; v0 = (ci - 128) * 16; }
    else if (ci < 320) { w = w1e; N = 1024; v0 = (ci - 256) * 16; }
    else               { w = w2e; N = 1024; v0 = (ci - 320) * 16; }
    int n = v0 + (l & 15);
    int k0 = kb * 32 + (l >> 4) * 8;
    u16x8 v;
#pragma unroll
    for (int e = 0; e < 8; ++e) v[e] = f2bf(w[(size_t)(k0 + e) * N + n]);
    ws[A_V8_TOTAL + tb] = v;
  }
}

// ---------------- main fused kernel ----------------
// Block = 4 waves sharing one mt2 (32-row A-slice), each wave a different vt.
// acc[mf][p][j] = y_p[m = mt2*32+mf*16+(l>>4)*4+j, v = vt*16+(l&15)]
__global__ __launch_bounds__(256) void tp_main(const u16x8* __restrict__ ws,
                                               float* __restrict__ out) {
  __shared__ float lds[4][4 * LROW];   // wave-private 3.2KB buffers, 12.8KB/block
  const int l = threadIdx.x & 63;
  const int wv = threadIdx.x >> 6;
  const int bid = blockIdx.x;
  const int logical = (bid & 7) * 1024 + (bid >> 3);  // bijective XCD swizzle
  const int mt2 = logical >> 5;                       // 0..255
  const int vt = ((logical & 31) << 2) | wv;          // 0..127
  const int l15 = l & 15, lhi = l >> 4;
  const u16x8* Ap = ws;
  const u16x8* Bp = ws + A_V8_TOTAL;
  float* lbuf = lds[wv];

  const float c3  = 0.57735026918962576f;   // 1/sqrt(3)
  const float c6  = 0.40824829046386302f;   // 1/sqrt(6)
  const float c10 = 0.31622776601683794f;   // 1/sqrt(10)
  const float c30 = 0.18257418583505537f;   // 1/sqrt(30)

  if (vt < 64) {
    // ---- region L: y0[v], y1o[v,0:3], y1e[v,0:3], y2e[v,0:5] -> C + D blocks
    f32x4 acc[2][12];
#pragma unroll
    for (int mf = 0; mf < 2; ++mf)
#pragma unroll
      for (int p = 0; p < 12; ++p) acc[mf][p] = (f32x4)(0.0f);

    const int ci0 = vt, ci1 = 128 + vt, ci2 = 256 + vt, ci3 = 320 + vt;
#pragma unroll
    for (int kb = 0; kb < 4; ++kb) {
      bf16x8 b0 = asbf(Bp[((ci0 << 2) + kb) * 64 + l]);
      bf16x8 b1 = asbf(Bp[((ci1 << 2) + kb) * 64 + l]);
      bf16x8 b2 = asbf(Bp[((ci2 << 2) + kb) * 64 + l]);
      bf16x8 b3 = asbf(Bp[((ci3 << 2) + kb) * 64 + l]);
#pragma unroll
      for (int mf = 0; mf < 2; ++mf) {
        const u16x8* ar = Ap + (((((mt2 << 1) | mf) << 2) + kb) << 6) + l;
        acc[mf][0]  = mfma16(asbf(ar[0]),             b0, acc[mf][0]);
        acc[mf][1]  = mfma16(asbf(ar[1 * P_STRIDE]),  b1, acc[mf][1]);
        acc[mf][2]  = mfma16(asbf(ar[2 * P_STRIDE]),  b1, acc[mf][2]);
        acc[mf][3]  = mfma16(asbf(ar[3 * P_STRIDE]),  b1, acc[mf][3]);
        acc[mf][4]  = mfma16(asbf(ar[4 * P_STRIDE]),  b2, acc[mf][4]);
        acc[mf][5]  = mfma16(asbf(ar[5 * P_STRIDE]),  b2, acc[mf][5]);
        acc[mf][6]  = mfma16(asbf(ar[6 * P_STRIDE]),  b2, acc[mf][6]);
        acc[mf][7]  = mfma16(asbf(ar[7 * P_STRIDE]),  b3, acc[mf][7]);
        acc[mf][8]  = mfma16(asbf(ar[8 * P_STRIDE]),  b3, acc[mf][8]);
        acc[mf][9]  = mfma16(asbf(ar[9 * P_STRIDE]),  b3, acc[mf][9]);
        acc[mf][10] = mfma16(asbf(ar[10 * P_STRIDE]), b3, acc[mf][10]);
        acc[mf][11] = mfma16(asbf(ar[11 * P_STRIDE]), b3, acc[mf][11]);
      }
    }
    // ---- epilogue: per (mf,j) stage 4 m-rows x 192 floats in LDS, drain
    // with full-line dwordx4 nt. Row r=lhi holds m16=lhi*4+j.
    // Row layout: [0,48) C (lam*16+v15), [48,192) D (lam*48+v15*3+rho).
    const int v5 = vt >> 1;
    const int vb0 = (vt & 1) << 4;
#pragma unroll
    for (int mf = 0; mf < 2; ++mf) {
#pragma unroll
      for (int j = 0; j < 4; ++j) {
        float* row = lbuf + lhi * LROW;
        // stage C
        row[0 * 16 + l15] = acc[mf][1][j] * c3;
        row[1 * 16 + l15] = acc[mf][2][j] * c3;
        row[2 * 16 + l15] = acc[mf][3][j] * c3;
        // stage D
        const float s  = acc[mf][0][j] * c3;
        const float e0 = acc[mf][4][j], e1 = acc[mf][5][j], e2 = acc[mf][6][j];
        const float q0 = acc[mf][7][j], q1 = acc[mf][8][j];
        const float q2 = acc[mf][9][j], q3 = acc[mf][10][j], q4 = acc[mf][11][j];
        float* rd = row + 48 + l15 * 3;
        // cg(1,1,1) = -eps/sqrt(6) (reference SVD sign)
        rd[0]      = s - q2 * c30 - q4 * c10;   // D[0][0]
        rd[1]      = -e2 * c6 + q1 * c10;       // D[0][1]
        rd[2]      = e1 * c6 + q0 * c10;        // D[0][2]
        rd[48 + 0] = e2 * c6 + q1 * c10;        // D[1][0]
        rd[48 + 1] = s + 2.0f * q2 * c30;       // D[1][1]
        rd[48 + 2] = -e0 * c6 + q3 * c10;       // D[1][2]
        rd[96 + 0] = -e1 * c6 + q0 * c10;       // D[2][0]
        rd[96 + 1] = e0 * c6 + q3 * c10;        // D[2][1]
        rd[96 + 2] = s - q2 * c30 + q4 * c10;   // D[2][2]
        lgkm0();
        // drain: 192 pieces of 16B; piece -> (r, c)
#pragma unroll
        for (int it = 0; it < 3; ++it) {
          const int piece = it * 64 + l;
          const int r = piece / 48;
          const int c = piece - r * 48;
          f32x4 v = *(const f32x4*)(lbuf + r * LROW + c * 4);
          const int m = mt2 * 32 + mf * 16 + r * 4 + j;
          float* orow = out + (size_t)m * 16384;
          float* dst;
          if (c < 12) {
            const int lam = c >> 2;
            dst = orow + 4096 + v5 * 96 + vb0 + lam * 32 + (c & 3) * 4;
          } else {
            const int cc = c - 12;
            const int lam = cc / 12;
            dst = orow + 7168 + v5 * 288 + vb0 * 3 + lam * 96 + (cc - lam * 12) * 4;
          }
          stnt4(dst, v);
        }
        lgkm0();  // drain reads done before next stage overwrites
      }
    }
  } else {
    // ---- region H: v' = v-1024; y0[v] -> A block, y1o[v,:] -> B block
    const int vtp = vt - 64;
    f32x4 acc[2][4];
#pragma unroll
    for (int mf = 0; mf < 2; ++mf)
#pragma unroll
      for (int p = 0; p < 4; ++p) acc[mf][p] = (f32x4)(0.0f);

    const int ci0 = 64 + vtp, ci1 = 192 + vtp;
#pragma unroll
    for (int kb = 0; kb < 4; ++kb) {
      bf16x8 b0 = asbf(Bp[((ci0 << 2) + kb) * 64 + l]);
      bf16x8 b1 = asbf(Bp[((ci1 << 2) + kb) * 64 + l]);
#pragma unroll
      for (int mf = 0; mf < 2; ++mf) {
        const u16x8* ar = Ap + (((((mt2 << 1) | mf) << 2) + kb) << 6) + l;
        acc[mf][0] = mfma16(asbf(ar[0]),            b0, acc[mf][0]);
        acc[mf][1] = mfma16(asbf(ar[1 * P_STRIDE]), b1, acc[mf][1]);
        acc[mf][2] = mfma16(asbf(ar[2 * P_STRIDE]), b1, acc[mf][2]);
        acc[mf][3] = mfma16(asbf(ar[3 * P_STRIDE]), b1, acc[mf][3]);
      }
    }
    // epilogue: row layout [0,16) A (v15), [16,64) B (v15*3+rho); 64 pieces/(mf,j)
#pragma unroll
    for (int mf = 0; mf < 2; ++mf) {
#pragma unroll
      for (int j = 0; j < 4; ++j) {
        float* row = lbuf + lhi * LROW;
        row[l15] = acc[mf][0][j];
        float* rb = row + 16 + l15 * 3;
        rb[0] = acc[mf][1][j] * c3;
        rb[1] = acc[mf][2][j] * c3;
        rb[2] = acc[mf][3][j] * c3;
        lgkm0();
        const int r = lhi, c = l15;
        f32x4 v = *(const f32x4*)(lbuf + r * LROW + c * 4);
        const int m = mt2 * 32 + mf * 16 + r * 4 + j;
        float* orow = out + (size_t)m * 16384;
        float* dst;
        if (c < 4) dst = orow + vtp * 16 + c * 4;
        else       dst = orow + 1024 + vtp * 48 + (c - 4) * 4;
        stnt4(dst, v);
        lgkm0();
      }
    }
  }
}

extern "C" void kernel_launch(void* const* d_in, const int* in_sizes, int n_in,
                              void* d_out, int out_size, void* d_ws, size_t ws_size,
                              hipStream_t stream) {
  if (ws_size < WS_NEED_BYTES) return;
  const float* x   = (const float*)d_in[0];
  const float* w0e = (const float*)d_in[1];
  const float* w1o = (const float*)d_in[2];
  const float* w1e = (const float*)d_in[3];
  const float* w2e = (const float*)d_in[4];
  u16x8* ws = (u16x8*)d_ws;
  float* out = (float*)d_out;

  prep_kernel<<<6528, 256, 0, stream>>>(x, w0e, w1o, w1e, w2e, ws);
  tp_main<<<8192, 256, 0, stream>>>(ws, out);
}